// Round 1
// baseline (249.417 us; speedup 1.0000x reference)
//
#include <hip/hip_runtime.h>
#include <hip/hip_bf16.h>
#include <stdint.h>

// MahalanobisEnsembleLoss: out = sum_l w[l] * mean_n( v^T M_l v ),  v = F[l,n,:] - MEAN[l,idx[n],:]
// Split-precision MFMA: q ~= vhi^T (Mhi+Mlo) vhi  +  vlo^T (M+M^T)hi vhi
#define LDIM 4
#define NDIM 16384
#define DDIM 512
#define CDIM 1000
#define BN 64
#define BK 32
#define NSTEPS (DDIM / BK)  // 16
#define WS_NEED (3ull * LDIM * DDIM * DDIM * 2ull)  // 6 MiB of bf16 M-splits

typedef __attribute__((ext_vector_type(8))) short bf16x8;
typedef __attribute__((ext_vector_type(4))) float f32x4;

__device__ __forceinline__ unsigned short f2bf(float x) {
  union { float f; uint32_t u; } v; v.f = x;
  uint32_t u = v.u;
  u += 0x7FFF + ((u >> 16) & 1);   // RNE
  return (unsigned short)(u >> 16);
}
__device__ __forceinline__ float bf2f(unsigned short h) {
  union { uint32_t u; float f; } v; v.u = ((uint32_t)h) << 16; return v.f;
}

// ---- LDS layout (dynamic, 131072 B total) ----
// VHI: [64 n][512 e] bf16, row 1024 B, 16B-granule XOR swizzle with (n&7)
// BB : [512 d][32 e] bf16, row 64 B, granule XOR with (d&3)
// VLO: [64 n][512 e] int8 (vlo * 4096), row 512 B, granule XOR with (n&7)
#define VHI_OFF 0
#define BB_OFF  65536
#define VLO_OFF 98304
#define LDS_BYTES 131072

__device__ __forceinline__ int vhi_addr(int n, int e) {
  return VHI_OFF + n * 1024 + (((e >> 3) ^ (n & 7)) << 4) + (e & 7) * 2;
}
__device__ __forceinline__ int vlo_addr(int n, int e) {
  return VLO_OFF + n * 512 + (((e >> 4) ^ (n & 7)) << 4) + (e & 15);
}
__device__ __forceinline__ int bb_addr(int d, int el) {
  return BB_OFF + d * 64 + (((el >> 3) ^ (d & 3)) << 4) + (el & 7) * 2;
}

__device__ __forceinline__ void stage_b(char* lds, const unsigned short* __restrict__ src,
                                        int e0, int t) {
#pragma unroll
  for (int dg = 0; dg < 8; ++dg) {
    int d = dg * 64 + (t >> 3);
    int el = (t & 7) * 4;
    uint2 val = *(const uint2*)(src + (size_t)d * DDIM + e0 + el);
    *(uint2*)(lds + bb_addr(d, el)) = val;
  }
}

__device__ __forceinline__ void mfma_phase(const char* lds, int wd, int lane,
                                           bf16x8 a0, bf16x8 a1, f32x4 acc[2][8]) {
#pragma unroll
  for (int df = 0; df < 8; ++df) {
    bf16x8 b = *(const bf16x8*)(lds + bb_addr(wd * 128 + df * 16 + (lane & 15),
                                              (lane >> 4) << 3));
    acc[0][df] = __builtin_amdgcn_mfma_f32_16x16x32_bf16(a0, b, acc[0][df], 0, 0, 0);
    acc[1][df] = __builtin_amdgcn_mfma_f32_16x16x32_bf16(a1, b, acc[1][df], 0, 0, 0);
  }
}

// K0: split inverse_cov into Mhi/Mlo bf16 and Msym2hi = bf16(M + M^T)
extern "C" __global__ void mel_msplit(const float* __restrict__ IC,
                                      unsigned short* __restrict__ MHI,
                                      unsigned short* __restrict__ MLO,
                                      unsigned short* __restrict__ MS2) {
  size_t i4 = (size_t)blockIdx.x * 256 + threadIdx.x;  // covers L*D*D/4
  size_t base = i4 * 4;
  int l = (int)(base >> 18);
  int rem = (int)(base & 262143);
  int d = rem >> 9;
  int e = rem & 511;
  float4 v = *(const float4*)(IC + base);
  const float* icl = IC + ((size_t)l << 18);
  float t0 = icl[(size_t)(e + 0) * DDIM + d];
  float t1 = icl[(size_t)(e + 1) * DDIM + d];
  float t2 = icl[(size_t)(e + 2) * DDIM + d];
  float t3 = icl[(size_t)(e + 3) * DDIM + d];
  ushort4 hh = make_ushort4(f2bf(v.x), f2bf(v.y), f2bf(v.z), f2bf(v.w));
  *(ushort4*)(MHI + base) = hh;
  ushort4 ll = make_ushort4(f2bf(v.x - bf2f(hh.x)), f2bf(v.y - bf2f(hh.y)),
                            f2bf(v.z - bf2f(hh.z)), f2bf(v.w - bf2f(hh.w)));
  *(ushort4*)(MLO + base) = ll;
  ushort4 ss = make_ushort4(f2bf(v.x + t0), f2bf(v.y + t1),
                            f2bf(v.z + t2), f2bf(v.w + t3));
  *(ushort4*)(MS2 + base) = ss;
}

// Main kernel: 512 threads = 8 waves (2 n-groups x 4 d-groups), BN=64 rows per block.
extern "C" __global__ __launch_bounds__(512, 2)
void mel_main(const float* __restrict__ F, const float* __restrict__ MEAN,
              const float* __restrict__ W, const int* __restrict__ IDX,
              const unsigned short* __restrict__ MHI,
              const unsigned short* __restrict__ MLO,
              const unsigned short* __restrict__ MS2,
              float* __restrict__ OUT) {
  extern __shared__ __align__(16) char lds[];
  const int t = threadIdx.x;
  const int lane = t & 63;
  const int w = t >> 6;
  const int wn = w & 1;   // n-group (2 x 32 rows)
  const int wd = w >> 1;  // d-group (4 x 128 cols)
  const int l = blockIdx.y;
  const int n0 = blockIdx.x * BN;

  // staging coords: thread -> (n = t>>3, e-run of 4 at (t&7)*4 within the BK chunk)
  const int sa_n = t >> 3;
  const int sa_e = (t & 7) << 2;
  const int cls = IDX[n0 + sa_n];  // top2_index is int32 on device (JAX x64 off)
  const size_t frow = ((size_t)l * NDIM + n0 + sa_n) * DDIM;
  const size_t mrow = ((size_t)l * CDIM + cls) * DDIM;

  const size_t msz = (size_t)DDIM * DDIM;
  const unsigned short* mhi_l = MHI + (size_t)l * msz;
  const unsigned short* mlo_l = MLO + (size_t)l * msz;
  const unsigned short* ms2_l = MS2 + (size_t)l * msz;

  f32x4 acc1[2][8];  // W_AB = Vhi (Mhi+Mlo)^T
  f32x4 acc2[2][8];  // W_C  = Vhi Msym2hi^T
#pragma unroll
  for (int i = 0; i < 2; ++i)
#pragma unroll
    for (int j = 0; j < 8; ++j) {
      acc1[i][j] = {0.f, 0.f, 0.f, 0.f};
      acc2[i][j] = {0.f, 0.f, 0.f, 0.f};
    }

  for (int s = 0; s < NSTEPS; ++s) {
    const int e0 = s * BK;
    // ---- stage A: gather mean, subtract, split; persist Vhi(bf16) + Vlo(int8*4096)
    {
      const int e = e0 + sa_e;
      const float4 f = *(const float4*)(F + frow + e);
      const float4 m = *(const float4*)(MEAN + mrow + e);
      float v0 = f.x - m.x, v1 = f.y - m.y, v2 = f.z - m.z, v3 = f.w - m.w;
      unsigned short h0 = f2bf(v0), h1 = f2bf(v1), h2 = f2bf(v2), h3 = f2bf(v3);
      *(ushort4*)(lds + vhi_addr(sa_n, e)) = make_ushort4(h0, h1, h2, h3);
      float l0 = v0 - bf2f(h0), l1 = v1 - bf2f(h1), l2 = v2 - bf2f(h2), l3 = v3 - bf2f(h3);
      int q0 = (int)rintf(l0 * 4096.f), q1 = (int)rintf(l1 * 4096.f);
      int q2 = (int)rintf(l2 * 4096.f), q3 = (int)rintf(l3 * 4096.f);
      q0 = q0 > 127 ? 127 : (q0 < -127 ? -127 : q0);
      q1 = q1 > 127 ? 127 : (q1 < -127 ? -127 : q1);
      q2 = q2 > 127 ? 127 : (q2 < -127 ? -127 : q2);
      q3 = q3 > 127 ? 127 : (q3 < -127 ? -127 : q3);
      *(char4*)(lds + vlo_addr(sa_n, e)) =
          make_char4((signed char)q0, (signed char)q1, (signed char)q2, (signed char)q3);
    }
    // ---- phase 1: Mhi
    stage_b(lds, mhi_l, e0, t);
    __syncthreads();
    bf16x8 a0 = *(const bf16x8*)(lds + vhi_addr(wn * 32 + (lane & 15),
                                                e0 + ((lane >> 4) << 3)));
    bf16x8 a1 = *(const bf16x8*)(lds + vhi_addr(wn * 32 + 16 + (lane & 15),
                                                e0 + ((lane >> 4) << 3)));
    mfma_phase(lds, wd, lane, a0, a1, acc1);
    __syncthreads();
    // ---- phase 2: Mlo (same accumulator -> effectively Vhi*(Mhi+Mlo))
    stage_b(lds, mlo_l, e0, t);
    __syncthreads();
    mfma_phase(lds, wd, lane, a0, a1, acc1);
    __syncthreads();
    // ---- phase 3: Msym2hi
    stage_b(lds, ms2_l, e0, t);
    __syncthreads();
    mfma_phase(lds, wd, lane, a0, a1, acc2);
    __syncthreads();
  }

  // ---- epilogue: q contributions. C-frag layout: col = lane&15 (d), row = (lane>>4)*4 + r (n)
  float tsum = 0.f;
#pragma unroll
  for (int nf = 0; nf < 2; ++nf) {
#pragma unroll
    for (int df = 0; df < 8; ++df) {
      const int dcol = wd * 128 + df * 16 + (lane & 15);
      const int nb = wn * 32 + nf * 16 + ((lane >> 4) << 2);
      f32x4 c1 = acc1[nf][df];
      f32x4 c2 = acc2[nf][df];
#pragma unroll
      for (int r = 0; r < 4; ++r) {
        const int n = nb + r;
        unsigned short hv = *(const unsigned short*)(lds + vhi_addr(n, dcol));
        signed char lv = *(const signed char*)(lds + vlo_addr(n, dcol));
        tsum += bf2f(hv) * c1[r] + (float)lv * (1.f / 4096.f) * c2[r];
      }
    }
  }
#pragma unroll
  for (int off = 32; off > 0; off >>= 1) tsum += __shfl_down(tsum, off);
  __syncthreads();
  float* red = (float*)(lds + BB_OFF);
  if (lane == 0) red[w] = tsum;
  __syncthreads();
  if (t == 0) {
    float ssum = 0.f;
#pragma unroll
    for (int i = 0; i < 8; ++i) ssum += red[i];
    atomicAdd(OUT, ssum * (W[l] / (float)NDIM));
  }
}

// Correct-but-slow fp32 fallback (only if ws_size < WS_NEED).
extern "C" __global__ void mel_fallback(const float* __restrict__ F,
                                        const float* __restrict__ MEAN,
                                        const float* __restrict__ IC,
                                        const float* __restrict__ W,
                                        const int* __restrict__ IDX,
                                        float* __restrict__ OUT) {
  __shared__ float v[8][DDIM];
  __shared__ float red[256];
  const int t = threadIdx.x;
  const int l = blockIdx.y;
  const int n0 = blockIdx.x * 8;
  for (int i = t; i < 8 * DDIM; i += 256) {
    int n = i >> 9, e = i & 511;
    int c = IDX[n0 + n];
    v[n][e] = F[((size_t)l * NDIM + n0 + n) * DDIM + e] -
              MEAN[((size_t)l * CDIM + c) * DDIM + e];
  }
  __syncthreads();
  const float* icl = IC + ((size_t)l << 18);
  float part = 0.f;
  for (int rep = 0; rep < 2; ++rep) {
    int d = t + rep * 256;
    float s[8];
#pragma unroll
    for (int j = 0; j < 8; ++j) s[j] = 0.f;
    for (int e = 0; e < DDIM; ++e) {
      float m = icl[(size_t)d * DDIM + e];
#pragma unroll
      for (int j = 0; j < 8; ++j) s[j] += m * v[j][e];
    }
#pragma unroll
    for (int j = 0; j < 8; ++j) part += v[j][d] * s[j];
  }
  red[t] = part;
  __syncthreads();
  for (int o = 128; o > 0; o >>= 1) {
    if (t < o) red[t] += red[t + o];
    __syncthreads();
  }
  if (t == 0) atomicAdd(OUT, red[0] * (W[l] / (float)NDIM));
}

extern "C" void kernel_launch(void* const* d_in, const int* in_sizes, int n_in,
                              void* d_out, int out_size, void* d_ws, size_t ws_size,
                              hipStream_t stream) {
  const float* F = (const float*)d_in[0];
  const float* MEAN = (const float*)d_in[1];
  const float* IC = (const float*)d_in[2];
  const float* W = (const float*)d_in[3];
  const int* IDX = (const int*)d_in[4];
  float* OUT = (float*)d_out;

  hipMemsetAsync(d_out, 0, sizeof(float) * (size_t)out_size, stream);

  if (ws_size >= WS_NEED) {
    unsigned short* MHI = (unsigned short*)d_ws;
    unsigned short* MLO = MHI + (size_t)LDIM * DDIM * DDIM;
    unsigned short* MS2 = MLO + (size_t)LDIM * DDIM * DDIM;
    mel_msplit<<<dim3(1024), dim3(256), 0, stream>>>(IC, MHI, MLO, MS2);
    (void)hipFuncSetAttribute(reinterpret_cast<const void*>(mel_main),
                              hipFuncAttributeMaxDynamicSharedMemorySize, LDS_BYTES);
    mel_main<<<dim3(NDIM / BN, LDIM), dim3(512), LDS_BYTES, stream>>>(
        F, MEAN, W, IDX, MHI, MLO, MS2, OUT);
  } else {
    mel_fallback<<<dim3(NDIM / 8, LDIM), dim3(256), 0, stream>>>(F, MEAN, IC, W, IDX, OUT);
  }
}

// Round 2
// 174.950 us; speedup vs baseline: 1.4256x; 1.4256x over previous
//
#include <hip/hip_runtime.h>
#include <hip/hip_bf16.h>
#include <stdint.h>

// MahalanobisEnsembleLoss: out = sum_l w[l] * mean_n( v^T M_l v ),  v = F[l,n,:] - MEAN[l,idx[n],:]
// Symmetric split-precision: S = (M+M^T)/2 = Shi + Slo (bf16+bf16), v = vhi + vlo(int8-quant)
//   q ~= vhi^T (Shi+Slo) vhi + 2 vlo^T Shi vhi
// GEMM1: W1 = Vhi Shi^T, GEMM2: W2 = Vhi Slo^T; epilogue q = vhi.(W1+W2) + (2 vlo).W1
#define LDIM 4
#define NDIM 16384
#define DDIM 512
#define CDIM 1000
#define BN 64
#define BK 32
#define NSTEPS (DDIM / BK)  // 16
#define WS_NEED (2ull * LDIM * DDIM * DDIM * 2ull)  // 4 MiB of bf16 S-splits

typedef __attribute__((ext_vector_type(8))) short bf16x8;
typedef __attribute__((ext_vector_type(4))) float f32x4;

__device__ __forceinline__ unsigned short f2bf(float x) {
  union { float f; uint32_t u; } v; v.f = x;
  uint32_t u = v.u;
  u += 0x7FFF + ((u >> 16) & 1);   // RNE
  return (unsigned short)(u >> 16);
}
__device__ __forceinline__ float bf2f(unsigned short h) {
  union { uint32_t u; float f; } v; v.u = ((uint32_t)h) << 16; return v.f;
}

// ---- LDS layout (dynamic, 98368 B) ----
// VHI: [64 n][512 e] bf16, row 1024 B, 16B-granule XOR swizzle with (n&7)
// VLO: [64 n][512 e] int8 (vlo * 4096), row 512 B, granule XOR with (n&7)
// RED: 16 floats (block reduction)
#define VHI_OFF 0
#define VLO_OFF 65536
#define RED_OFF 98304
#define LDS_BYTES 98368

__device__ __forceinline__ int vhi_addr(int n, int e) {
  return VHI_OFF + n * 1024 + (((e >> 3) ^ (n & 7)) << 4) + (e & 7) * 2;
}
__device__ __forceinline__ int vlo_addr(int n, int e) {
  return VLO_OFF + n * 512 + (((e >> 4) ^ (n & 7)) << 4) + (e & 15);
}

// K0: S = 0.5*(M + M^T); SHI = bf16(S), SLO = bf16(S - SHI). Symmetry is exact
// (both (d,e) and (e,d) threads compute the identical fp32 S before rounding).
extern "C" __global__ void mel_msplit(const float* __restrict__ IC,
                                      unsigned short* __restrict__ SHI,
                                      unsigned short* __restrict__ SLO) {
  size_t i4 = (size_t)blockIdx.x * 256 + threadIdx.x;  // covers L*D*D/4
  size_t base = i4 * 4;
  int l = (int)(base >> 18);
  int rem = (int)(base & 262143);
  int d = rem >> 9;
  int e = rem & 511;
  float4 v = *(const float4*)(IC + base);
  const float* icl = IC + ((size_t)l << 18);
  float t0 = icl[(size_t)(e + 0) * DDIM + d];
  float t1 = icl[(size_t)(e + 1) * DDIM + d];
  float t2 = icl[(size_t)(e + 2) * DDIM + d];
  float t3 = icl[(size_t)(e + 3) * DDIM + d];
  float s0 = 0.5f * (v.x + t0), s1 = 0.5f * (v.y + t1);
  float s2 = 0.5f * (v.z + t2), s3 = 0.5f * (v.w + t3);
  ushort4 hh = make_ushort4(f2bf(s0), f2bf(s1), f2bf(s2), f2bf(s3));
  *(ushort4*)(SHI + base) = hh;
  ushort4 ll = make_ushort4(f2bf(s0 - bf2f(hh.x)), f2bf(s1 - bf2f(hh.y)),
                            f2bf(s2 - bf2f(hh.z)), f2bf(s3 - bf2f(hh.w)));
  *(ushort4*)(SLO + base) = ll;
}

// Main kernel: 1024 threads = 16 waves, each wave owns a unique 32-col d-slice
// (w*32) x all 64 rows. V persists in LDS; B-frags load straight from L2.
// K-loop has ZERO barriers.
extern "C" __global__ __launch_bounds__(1024, 4)
void mel_main(const float* __restrict__ F, const float* __restrict__ MEAN,
              const float* __restrict__ W, const int* __restrict__ IDX,
              const unsigned short* __restrict__ SHI,
              float* __restrict__ OUT) {
  extern __shared__ __align__(16) char lds[];
  const int t = threadIdx.x;
  const int lane = t & 63;
  const int w = t >> 6;          // 16 waves
  const int l = blockIdx.y;
  const int n0 = blockIdx.x * BN;
  const int col0 = w * 32;       // wave's d-column base
  const int lrow = lane & 15;
  const int lke = (lane >> 4) << 3;  // 0,8,16,24

  // ---- stage V: gather mean, subtract, split; persist Vhi(bf16) + Vlo(int8*4096)
  {
    const int sn = t >> 4;          // wave w covers rows w*4..w*4+3
    const int be = (t & 15) << 2;   // lanes 0-15: contiguous float4s
    const int cls = IDX[n0 + sn];   // top2_index -> int32 on device
    const float* fr = F + ((size_t)l * NDIM + n0 + sn) * DDIM;
    const float* mr = MEAN + ((size_t)l * CDIM + cls) * DDIM;
#pragma unroll
    for (int j = 0; j < 8; ++j) {
      const int e = be + j * 64;
      const float4 f = *(const float4*)(fr + e);
      const float4 m = *(const float4*)(mr + e);
      float v0 = f.x - m.x, v1 = f.y - m.y, v2 = f.z - m.z, v3 = f.w - m.w;
      unsigned short h0 = f2bf(v0), h1 = f2bf(v1), h2 = f2bf(v2), h3 = f2bf(v3);
      *(ushort4*)(lds + vhi_addr(sn, e)) = make_ushort4(h0, h1, h2, h3);
      float l0 = v0 - bf2f(h0), l1 = v1 - bf2f(h1);
      float l2 = v2 - bf2f(h2), l3 = v3 - bf2f(h3);
      int q0 = (int)rintf(l0 * 4096.f), q1 = (int)rintf(l1 * 4096.f);
      int q2 = (int)rintf(l2 * 4096.f), q3 = (int)rintf(l3 * 4096.f);
      q0 = q0 > 127 ? 127 : (q0 < -127 ? -127 : q0);
      q1 = q1 > 127 ? 127 : (q1 < -127 ? -127 : q1);
      q2 = q2 > 127 ? 127 : (q2 < -127 ? -127 : q2);
      q3 = q3 > 127 ? 127 : (q3 < -127 ? -127 : q3);
      *(char4*)(lds + vlo_addr(sn, e)) =
          make_char4((signed char)q0, (signed char)q1, (signed char)q2, (signed char)q3);
    }
  }
  __syncthreads();  // the ONLY barrier before the epilogue

  const size_t msz = (size_t)DDIM * DDIM;
  const size_t slo_delta = (size_t)LDIM * msz;  // SLO = SHI + L*D*D elements
  const unsigned short* shi_l = SHI + (size_t)l * msz;

  f32x4 acc1[4][2];  // W1 = Vhi Shi^T   [n-frag][d-frag]
  f32x4 acc2[4][2];  // W2 = Vhi Slo^T
#pragma unroll
  for (int i = 0; i < 4; ++i)
#pragma unroll
    for (int j = 0; j < 2; ++j) {
      acc1[i][j] = {0.f, 0.f, 0.f, 0.f};
      acc2[i][j] = {0.f, 0.f, 0.f, 0.f};
    }

  // ---- K-loop: no barriers. A from LDS, B straight from L2.
  for (int s = 0; s < NSTEPS; ++s) {
    const int e0 = s * BK;
    bf16x8 a0 = *(const bf16x8*)(lds + vhi_addr(lrow, e0 + lke));
    bf16x8 a1 = *(const bf16x8*)(lds + vhi_addr(16 + lrow, e0 + lke));
    bf16x8 a2 = *(const bf16x8*)(lds + vhi_addr(32 + lrow, e0 + lke));
    bf16x8 a3 = *(const bf16x8*)(lds + vhi_addr(48 + lrow, e0 + lke));
    const unsigned short* bp = shi_l + (size_t)(col0 + lrow) * DDIM + e0 + lke;
    bf16x8 b0h = *(const bf16x8*)(bp);
    bf16x8 b1h = *(const bf16x8*)(bp + 16 * DDIM);
    bf16x8 b0l = *(const bf16x8*)(bp + slo_delta);
    bf16x8 b1l = *(const bf16x8*)(bp + slo_delta + 16 * DDIM);
    acc1[0][0] = __builtin_amdgcn_mfma_f32_16x16x32_bf16(a0, b0h, acc1[0][0], 0, 0, 0);
    acc1[1][0] = __builtin_amdgcn_mfma_f32_16x16x32_bf16(a1, b0h, acc1[1][0], 0, 0, 0);
    acc1[2][0] = __builtin_amdgcn_mfma_f32_16x16x32_bf16(a2, b0h, acc1[2][0], 0, 0, 0);
    acc1[3][0] = __builtin_amdgcn_mfma_f32_16x16x32_bf16(a3, b0h, acc1[3][0], 0, 0, 0);
    acc1[0][1] = __builtin_amdgcn_mfma_f32_16x16x32_bf16(a0, b1h, acc1[0][1], 0, 0, 0);
    acc1[1][1] = __builtin_amdgcn_mfma_f32_16x16x32_bf16(a1, b1h, acc1[1][1], 0, 0, 0);
    acc1[2][1] = __builtin_amdgcn_mfma_f32_16x16x32_bf16(a2, b1h, acc1[2][1], 0, 0, 0);
    acc1[3][1] = __builtin_amdgcn_mfma_f32_16x16x32_bf16(a3, b1h, acc1[3][1], 0, 0, 0);
    acc2[0][0] = __builtin_amdgcn_mfma_f32_16x16x32_bf16(a0, b0l, acc2[0][0], 0, 0, 0);
    acc2[1][0] = __builtin_amdgcn_mfma_f32_16x16x32_bf16(a1, b0l, acc2[1][0], 0, 0, 0);
    acc2[2][0] = __builtin_amdgcn_mfma_f32_16x16x32_bf16(a2, b0l, acc2[2][0], 0, 0, 0);
    acc2[3][0] = __builtin_amdgcn_mfma_f32_16x16x32_bf16(a3, b0l, acc2[3][0], 0, 0, 0);
    acc2[0][1] = __builtin_amdgcn_mfma_f32_16x16x32_bf16(a0, b1l, acc2[0][1], 0, 0, 0);
    acc2[1][1] = __builtin_amdgcn_mfma_f32_16x16x32_bf16(a1, b1l, acc2[1][1], 0, 0, 0);
    acc2[2][1] = __builtin_amdgcn_mfma_f32_16x16x32_bf16(a2, b1l, acc2[2][1], 0, 0, 0);
    acc2[3][1] = __builtin_amdgcn_mfma_f32_16x16x32_bf16(a3, b1l, acc2[3][1], 0, 0, 0);
  }

  // ---- epilogue: q = vhi.(W1+W2) + (2*vlo).W1
  // C-frag layout: col = lane&15 (d), row = (lane>>4)*4 + r (n)
  float tsum = 0.f;
#pragma unroll
  for (int nf = 0; nf < 4; ++nf) {
#pragma unroll
    for (int df = 0; df < 2; ++df) {
      const int dcol = col0 + df * 16 + lrow;
      const int nb = nf * 16 + ((lane >> 4) << 2);
      f32x4 c1 = acc1[nf][df];
      f32x4 c2 = acc2[nf][df];
#pragma unroll
      for (int r = 0; r < 4; ++r) {
        const int n = nb + r;
        unsigned short hv = *(const unsigned short*)(lds + vhi_addr(n, dcol));
        signed char lv = *(const signed char*)(lds + vlo_addr(n, dcol));
        tsum += bf2f(hv) * (c1[r] + c2[r]) + (float)lv * (1.f / 2048.f) * c1[r];
      }
    }
  }
#pragma unroll
  for (int off = 32; off > 0; off >>= 1) tsum += __shfl_down(tsum, off);
  __syncthreads();
  float* red = (float*)(lds + RED_OFF);
  if (lane == 0) red[w] = tsum;
  __syncthreads();
  if (t == 0) {
    float ssum = 0.f;
#pragma unroll
    for (int i = 0; i < 16; ++i) ssum += red[i];
    atomicAdd(OUT, ssum * (W[l] / (float)NDIM));
  }
}

// Correct-but-slow fp32 fallback (only if ws_size < WS_NEED).
extern "C" __global__ void mel_fallback(const float* __restrict__ F,
                                        const float* __restrict__ MEAN,
                                        const float* __restrict__ IC,
                                        const float* __restrict__ W,
                                        const int* __restrict__ IDX,
                                        float* __restrict__ OUT) {
  __shared__ float v[8][DDIM];
  __shared__ float red[256];
  const int t = threadIdx.x;
  const int l = blockIdx.y;
  const int n0 = blockIdx.x * 8;
  for (int i = t; i < 8 * DDIM; i += 256) {
    int n = i >> 9, e = i & 511;
    int c = IDX[n0 + n];
    v[n][e] = F[((size_t)l * NDIM + n0 + n) * DDIM + e] -
              MEAN[((size_t)l * CDIM + c) * DDIM + e];
  }
  __syncthreads();
  const float* icl = IC + ((size_t)l << 18);
  float part = 0.f;
  for (int rep = 0; rep < 2; ++rep) {
    int d = t + rep * 256;
    float s[8];
#pragma unroll
    for (int j = 0; j < 8; ++j) s[j] = 0.f;
    for (int e = 0; e < DDIM; ++e) {
      float m = icl[(size_t)d * DDIM + e];
#pragma unroll
      for (int j = 0; j < 8; ++j) s[j] += m * v[j][e];
    }
#pragma unroll
    for (int j = 0; j < 8; ++j) part += v[j][d] * s[j];
  }
  red[t] = part;
  __syncthreads();
  for (int o = 128; o > 0; o >>= 1) {
    if (t < o) red[t] += red[t + o];
    __syncthreads();
  }
  if (t == 0) atomicAdd(OUT, red[0] * (W[l] / (float)NDIM));
}

extern "C" void kernel_launch(void* const* d_in, const int* in_sizes, int n_in,
                              void* d_out, int out_size, void* d_ws, size_t ws_size,
                              hipStream_t stream) {
  const float* F = (const float*)d_in[0];
  const float* MEAN = (const float*)d_in[1];
  const float* IC = (const float*)d_in[2];
  const float* W = (const float*)d_in[3];
  const int* IDX = (const int*)d_in[4];
  float* OUT = (float*)d_out;

  hipMemsetAsync(d_out, 0, sizeof(float) * (size_t)out_size, stream);

  if (ws_size >= WS_NEED) {
    unsigned short* SHI = (unsigned short*)d_ws;
    unsigned short* SLO = SHI + (size_t)LDIM * DDIM * DDIM;
    mel_msplit<<<dim3(1024), dim3(256), 0, stream>>>(IC, SHI, SLO);
    (void)hipFuncSetAttribute(reinterpret_cast<const void*>(mel_main),
                              hipFuncAttributeMaxDynamicSharedMemorySize, LDS_BYTES);
    mel_main<<<dim3(NDIM / BN, LDIM), dim3(1024), LDS_BYTES, stream>>>(
        F, MEAN, W, IDX, SHI, OUT);
  } else {
    mel_fallback<<<dim3(NDIM / 8, LDIM), dim3(256), 0, stream>>>(F, MEAN, IC, W, IDX, OUT);
  }
}

// Round 3
// 167.977 us; speedup vs baseline: 1.4848x; 1.0415x over previous
//
#include <hip/hip_runtime.h>
#include <hip/hip_bf16.h>
#include <stdint.h>

// MahalanobisEnsembleLoss: out = sum_l w[l] * mean_n( v^T M_l v ),  v = F[l,n,:] - MEAN[l,idx[n],:]
// Symmetric split-precision: S = (M+M^T)/2 = Shi + Slo (bf16+bf16), v = vhi + vlo(int8-quant)
//   q ~= vhi^T (Shi+Slo) vhi + 2 vlo^T Shi vhi
// GEMM1: W1 = Vhi Shi^T, GEMM2: W2 = Vhi Slo^T; epilogue q = vhi.(W1+W2) + (2 vlo).W1
#define LDIM 4
#define NDIM 16384
#define DDIM 512
#define CDIM 1000
#define BN 64
#define BK 32
#define NSTEPS (DDIM / BK)  // 16
#define WS_NEED (2ull * LDIM * DDIM * DDIM * 2ull)  // 4 MiB of bf16 S-splits

typedef __attribute__((ext_vector_type(8))) short bf16x8;
typedef __attribute__((ext_vector_type(4))) float f32x4;

__device__ __forceinline__ unsigned short f2bf(float x) {
  union { float f; uint32_t u; } v; v.f = x;
  uint32_t u = v.u;
  u += 0x7FFF + ((u >> 16) & 1);   // RNE
  return (unsigned short)(u >> 16);
}
__device__ __forceinline__ float bf2f(unsigned short h) {
  union { uint32_t u; float f; } v; v.u = ((uint32_t)h) << 16; return v.f;
}

// ---- LDS layout (dynamic, 98368 B) ----
// VHI: [64 n][512 e] bf16, row 1024 B, 16B-granule XOR swizzle with (n&7)
// VLO: [64 n][512 e] int8 (vlo * 4096), row 512 B, granule XOR with (n&7)
// RED: 16 floats (block reduction)
#define VHI_OFF 0
#define VLO_OFF 65536
#define RED_OFF 98304
#define LDS_BYTES 98368

__device__ __forceinline__ int vhi_addr(int n, int e) {
  return VHI_OFF + n * 1024 + (((e >> 3) ^ (n & 7)) << 4) + (e & 7) * 2;
}
__device__ __forceinline__ int vlo_addr(int n, int e) {
  return VLO_OFF + n * 512 + (((e >> 4) ^ (n & 7)) << 4) + (e & 15);
}

// K0: S = 0.5*(M + M^T); SHI = bf16(S), SLO = bf16(S - SHI). Symmetry is exact
// (both (d,e) and (e,d) threads compute the identical fp32 S before rounding).
extern "C" __global__ void mel_msplit(const float* __restrict__ IC,
                                      unsigned short* __restrict__ SHI,
                                      unsigned short* __restrict__ SLO) {
  size_t i4 = (size_t)blockIdx.x * 256 + threadIdx.x;  // covers L*D*D/4
  size_t base = i4 * 4;
  int l = (int)(base >> 18);
  int rem = (int)(base & 262143);
  int d = rem >> 9;
  int e = rem & 511;
  float4 v = *(const float4*)(IC + base);
  const float* icl = IC + ((size_t)l << 18);
  float t0 = icl[(size_t)(e + 0) * DDIM + d];
  float t1 = icl[(size_t)(e + 1) * DDIM + d];
  float t2 = icl[(size_t)(e + 2) * DDIM + d];
  float t3 = icl[(size_t)(e + 3) * DDIM + d];
  float s0 = 0.5f * (v.x + t0), s1 = 0.5f * (v.y + t1);
  float s2 = 0.5f * (v.z + t2), s3 = 0.5f * (v.w + t3);
  ushort4 hh = make_ushort4(f2bf(s0), f2bf(s1), f2bf(s2), f2bf(s3));
  *(ushort4*)(SHI + base) = hh;
  ushort4 ll = make_ushort4(f2bf(s0 - bf2f(hh.x)), f2bf(s1 - bf2f(hh.y)),
                            f2bf(s2 - bf2f(hh.z)), f2bf(s3 - bf2f(hh.w)));
  *(ushort4*)(SLO + base) = ll;
}

// Main kernel: 1024 threads = 16 waves, each wave owns a unique 32-col d-slice.
// V persists in LDS; B-frags load straight from L2 with explicit 2-stage prefetch.
// K-loop has ZERO barriers. 1-D grid, XCD-aware decode: xcd pair owns one l.
extern "C" __global__ __launch_bounds__(1024, 2)
void mel_main(const float* __restrict__ F, const float* __restrict__ MEAN,
              const float* __restrict__ W, const int* __restrict__ IDX,
              const unsigned short* __restrict__ SHI,
              float* __restrict__ OUT) {
  extern __shared__ __align__(16) char lds[];
  const int t = threadIdx.x;
  const int lane = t & 63;
  const int w = t >> 6;          // 16 waves
  // XCD-aware decode: bid&7 -> XCD (heuristic); 2 XCDs per l, 128 bx each.
  const int bid = blockIdx.x;
  const int xcd = bid & 7;
  const int l = xcd >> 1;
  const int bx = (bid >> 3) + ((xcd & 1) << 7);
  const int n0 = bx * BN;
  const int col0 = w * 32;       // wave's d-column base
  const int lrow = lane & 15;
  const int lke = (lane >> 4) << 3;  // 0,8,16,24

  // ---- stage V: gather mean, subtract, split; persist Vhi(bf16) + Vlo(int8*4096)
  {
    const int sn = t >> 4;          // 64 rows, 16 threads/row
    const int be = (t & 15) << 2;   // lanes 0-15: contiguous float4s
    const int cls = IDX[n0 + sn];   // top2_index -> int32 on device
    const float4* fr = (const float4*)(F + ((size_t)l * NDIM + n0 + sn) * DDIM);
    const float4* mr = (const float4*)(MEAN + ((size_t)l * CDIM + cls) * DDIM);
    float4 fv[8], mv[8];
#pragma unroll
    for (int j = 0; j < 8; ++j) fv[j] = fr[(be >> 2) + j * 16];
#pragma unroll
    for (int j = 0; j < 8; ++j) mv[j] = mr[(be >> 2) + j * 16];
#pragma unroll
    for (int j = 0; j < 8; ++j) {
      const int e = be + j * 64;
      float v0 = fv[j].x - mv[j].x, v1 = fv[j].y - mv[j].y;
      float v2 = fv[j].z - mv[j].z, v3 = fv[j].w - mv[j].w;
      unsigned short h0 = f2bf(v0), h1 = f2bf(v1), h2 = f2bf(v2), h3 = f2bf(v3);
      *(ushort4*)(lds + vhi_addr(sn, e)) = make_ushort4(h0, h1, h2, h3);
      float l0 = v0 - bf2f(h0), l1 = v1 - bf2f(h1);
      float l2 = v2 - bf2f(h2), l3 = v3 - bf2f(h3);
      int q0 = (int)rintf(l0 * 4096.f), q1 = (int)rintf(l1 * 4096.f);
      int q2 = (int)rintf(l2 * 4096.f), q3 = (int)rintf(l3 * 4096.f);
      q0 = q0 > 127 ? 127 : (q0 < -127 ? -127 : q0);
      q1 = q1 > 127 ? 127 : (q1 < -127 ? -127 : q1);
      q2 = q2 > 127 ? 127 : (q2 < -127 ? -127 : q2);
      q3 = q3 > 127 ? 127 : (q3 < -127 ? -127 : q3);
      *(char4*)(lds + vlo_addr(sn, e)) =
          make_char4((signed char)q0, (signed char)q1, (signed char)q2, (signed char)q3);
    }
  }
  __syncthreads();  // the ONLY barrier before the epilogue

  const size_t msz = (size_t)DDIM * DDIM;
  const size_t slo_delta = (size_t)LDIM * msz;  // SLO = SHI + L*D*D elements
  const unsigned short* shi_l = SHI + (size_t)l * msz;

  f32x4 acc1[4][2];  // W1 = Vhi Shi^T   [n-frag][d-frag]
  f32x4 acc2[4][2];  // W2 = Vhi Slo^T
#pragma unroll
  for (int i = 0; i < 4; ++i)
#pragma unroll
    for (int j = 0; j < 2; ++j) {
      acc1[i][j] = {0.f, 0.f, 0.f, 0.f};
      acc2[i][j] = {0.f, 0.f, 0.f, 0.f};
    }

  // ---- K-loop: no barriers. A from LDS, B from L2 with 2-stage prefetch.
  const unsigned short* bp = shi_l + (size_t)(col0 + lrow) * DDIM + lke;
  bf16x8 b0h = *(const bf16x8*)(bp);
  bf16x8 b1h = *(const bf16x8*)(bp + 16 * DDIM);
  bf16x8 b0l = *(const bf16x8*)(bp + slo_delta);
  bf16x8 b1l = *(const bf16x8*)(bp + slo_delta + 16 * DDIM);
#pragma unroll 2
  for (int s = 0; s < NSTEPS; ++s) {
    const int e0 = s * BK;
    bf16x8 nb0h, nb1h, nb0l, nb1l;
    if (s < NSTEPS - 1) {  // prefetch next step's B before this step's MFMAs
      const unsigned short* np = bp + (s + 1) * BK;
      nb0h = *(const bf16x8*)(np);
      nb1h = *(const bf16x8*)(np + 16 * DDIM);
      nb0l = *(const bf16x8*)(np + slo_delta);
      nb1l = *(const bf16x8*)(np + slo_delta + 16 * DDIM);
    }
    bf16x8 a0 = *(const bf16x8*)(lds + vhi_addr(lrow, e0 + lke));
    bf16x8 a1 = *(const bf16x8*)(lds + vhi_addr(16 + lrow, e0 + lke));
    bf16x8 a2 = *(const bf16x8*)(lds + vhi_addr(32 + lrow, e0 + lke));
    bf16x8 a3 = *(const bf16x8*)(lds + vhi_addr(48 + lrow, e0 + lke));
    acc1[0][0] = __builtin_amdgcn_mfma_f32_16x16x32_bf16(a0, b0h, acc1[0][0], 0, 0, 0);
    acc1[1][0] = __builtin_amdgcn_mfma_f32_16x16x32_bf16(a1, b0h, acc1[1][0], 0, 0, 0);
    acc1[2][0] = __builtin_amdgcn_mfma_f32_16x16x32_bf16(a2, b0h, acc1[2][0], 0, 0, 0);
    acc1[3][0] = __builtin_amdgcn_mfma_f32_16x16x32_bf16(a3, b0h, acc1[3][0], 0, 0, 0);
    acc1[0][1] = __builtin_amdgcn_mfma_f32_16x16x32_bf16(a0, b1h, acc1[0][1], 0, 0, 0);
    acc1[1][1] = __builtin_amdgcn_mfma_f32_16x16x32_bf16(a1, b1h, acc1[1][1], 0, 0, 0);
    acc1[2][1] = __builtin_amdgcn_mfma_f32_16x16x32_bf16(a2, b1h, acc1[2][1], 0, 0, 0);
    acc1[3][1] = __builtin_amdgcn_mfma_f32_16x16x32_bf16(a3, b1h, acc1[3][1], 0, 0, 0);
    acc2[0][0] = __builtin_amdgcn_mfma_f32_16x16x32_bf16(a0, b0l, acc2[0][0], 0, 0, 0);
    acc2[1][0] = __builtin_amdgcn_mfma_f32_16x16x32_bf16(a1, b0l, acc2[1][0], 0, 0, 0);
    acc2[2][0] = __builtin_amdgcn_mfma_f32_16x16x32_bf16(a2, b0l, acc2[2][0], 0, 0, 0);
    acc2[3][0] = __builtin_amdgcn_mfma_f32_16x16x32_bf16(a3, b0l, acc2[3][0], 0, 0, 0);
    acc2[0][1] = __builtin_amdgcn_mfma_f32_16x16x32_bf16(a0, b1l, acc2[0][1], 0, 0, 0);
    acc2[1][1] = __builtin_amdgcn_mfma_f32_16x16x32_bf16(a1, b1l, acc2[1][1], 0, 0, 0);
    acc2[2][1] = __builtin_amdgcn_mfma_f32_16x16x32_bf16(a2, b1l, acc2[2][1], 0, 0, 0);
    acc2[3][1] = __builtin_amdgcn_mfma_f32_16x16x32_bf16(a3, b1l, acc2[3][1], 0, 0, 0);
    b0h = nb0h; b1h = nb1h; b0l = nb0l; b1l = nb1l;
  }

  // ---- epilogue: q = vhi.(W1+W2) + (2*vlo).W1
  // C-frag layout: col = lane&15 (d), row = (lane>>4)*4 + r (n)
  float tsum = 0.f;
#pragma unroll
  for (int nf = 0; nf < 4; ++nf) {
#pragma unroll
    for (int df = 0; df < 2; ++df) {
      const int dcol = col0 + df * 16 + lrow;
      const int nb = nf * 16 + ((lane >> 4) << 2);
      f32x4 c1 = acc1[nf][df];
      f32x4 c2 = acc2[nf][df];
#pragma unroll
      for (int r = 0; r < 4; ++r) {
        const int n = nb + r;
        unsigned short hv = *(const unsigned short*)(lds + vhi_addr(n, dcol));
        signed char lv = *(const signed char*)(lds + vlo_addr(n, dcol));
        tsum += bf2f(hv) * (c1[r] + c2[r]) + (float)lv * (1.f / 2048.f) * c1[r];
      }
    }
  }
#pragma unroll
  for (int off = 32; off > 0; off >>= 1) tsum += __shfl_down(tsum, off);
  __syncthreads();
  float* red = (float*)(lds + RED_OFF);
  if (lane == 0) red[w] = tsum;
  __syncthreads();
  if (t == 0) {
    float ssum = 0.f;
#pragma unroll
    for (int i = 0; i < 16; ++i) ssum += red[i];
    atomicAdd(OUT, ssum * (W[l] / (float)NDIM));
  }
}

// Correct-but-slow fp32 fallback (only if ws_size < WS_NEED).
extern "C" __global__ void mel_fallback(const float* __restrict__ F,
                                        const float* __restrict__ MEAN,
                                        const float* __restrict__ IC,
                                        const float* __restrict__ W,
                                        const int* __restrict__ IDX,
                                        float* __restrict__ OUT) {
  __shared__ float v[8][DDIM];
  __shared__ float red[256];
  const int t = threadIdx.x;
  const int l = blockIdx.y;
  const int n0 = blockIdx.x * 8;
  for (int i = t; i < 8 * DDIM; i += 256) {
    int n = i >> 9, e = i & 511;
    int c = IDX[n0 + n];
    v[n][e] = F[((size_t)l * NDIM + n0 + n) * DDIM + e] -
              MEAN[((size_t)l * CDIM + c) * DDIM + e];
  }
  __syncthreads();
  const float* icl = IC + ((size_t)l << 18);
  float part = 0.f;
  for (int rep = 0; rep < 2; ++rep) {
    int d = t + rep * 256;
    float s[8];
#pragma unroll
    for (int j = 0; j < 8; ++j) s[j] = 0.f;
    for (int e = 0; e < DDIM; ++e) {
      float m = icl[(size_t)d * DDIM + e];
#pragma unroll
      for (int j = 0; j < 8; ++j) s[j] += m * v[j][e];
    }
#pragma unroll
    for (int j = 0; j < 8; ++j) part += v[j][d] * s[j];
  }
  red[t] = part;
  __syncthreads();
  for (int o = 128; o > 0; o >>= 1) {
    if (t < o) red[t] += red[t + o];
    __syncthreads();
  }
  if (t == 0) atomicAdd(OUT, red[0] * (W[l] / (float)NDIM));
}

extern "C" void kernel_launch(void* const* d_in, const int* in_sizes, int n_in,
                              void* d_out, int out_size, void* d_ws, size_t ws_size,
                              hipStream_t stream) {
  const float* F = (const float*)d_in[0];
  const float* MEAN = (const float*)d_in[1];
  const float* IC = (const float*)d_in[2];
  const float* W = (const float*)d_in[3];
  const int* IDX = (const int*)d_in[4];
  float* OUT = (float*)d_out;

  hipMemsetAsync(d_out, 0, sizeof(float) * (size_t)out_size, stream);

  if (ws_size >= WS_NEED) {
    unsigned short* SHI = (unsigned short*)d_ws;
    unsigned short* SLO = SHI + (size_t)LDIM * DDIM * DDIM;
    mel_msplit<<<dim3(1024), dim3(256), 0, stream>>>(IC, SHI, SLO);
    (void)hipFuncSetAttribute(reinterpret_cast<const void*>(mel_main),
                              hipFuncAttributeMaxDynamicSharedMemorySize, LDS_BYTES);
    mel_main<<<dim3(1024), dim3(1024), LDS_BYTES, stream>>>(
        F, MEAN, W, IDX, SHI, OUT);
  } else {
    mel_fallback<<<dim3(NDIM / 8, LDIM), dim3(256), 0, stream>>>(F, MEAN, IC, W, IDX, OUT);
  }
}

// Round 4
// 99.870 us; speedup vs baseline: 2.4974x; 1.6820x over previous
//
#include <hip/hip_runtime.h>
#include <hip/hip_bf16.h>
#include <stdint.h>

// MahalanobisEnsembleLoss: out = sum_l w[l] * mean_n( v^T M_l v ),  v = F[l,n,:] - MEAN[l,idx[n],:]
// FP16 path: q ~= vh^T Mh vh with vh = fp16(v), Mh = fp16(M). Error ~0.01 << 0.09 threshold
// (fp16 rel 2^-11; dominant systematic term tr(dS*G)/N ~ 0.005).
// Single GEMM: acc = Vh * Mh^T (K=512), epilogue q = sum_d vh[n,d]*acc[n,d].
#define LDIM 4
#define NDIM 16384
#define DDIM 512
#define CDIM 1000
#define BN 64
#define BK 32
#define NSTEPS (DDIM / BK)  // 16
#define WS_NEED ((size_t)LDIM * DDIM * DDIM * 2)  // 2 MiB fp16 M

typedef __attribute__((ext_vector_type(8))) _Float16 f16x8;
typedef __attribute__((ext_vector_type(4))) float f32x4;

__device__ __forceinline__ unsigned short f2h(float x) {
  union { _Float16 h; unsigned short u; } c;
  c.h = (_Float16)x;  // RNE
  return c.u;
}
__device__ __forceinline__ float h2f(unsigned short u) {
  union { unsigned short u; _Float16 h; } c;
  c.u = u;
  return (float)c.h;
}

// ---- LDS: VH [64 n][512 e] fp16, row 1024 B, 16B-granule XOR swizzle with (n&7) ----
#define LDS_BYTES 65536
__device__ __forceinline__ int vh_addr(int n, int e) {
  return n * 1024 + (((e >> 3) ^ (n & 7)) << 4) + (e & 7) * 2;
}

// K0: convert M fp32 -> fp16 (RNE). 1024 blocks x 256 thr x 4 elems = L*D*D.
extern "C" __global__ void mel_mconv(const float* __restrict__ IC,
                                     unsigned short* __restrict__ MH) {
  size_t i = ((size_t)blockIdx.x * 256 + threadIdx.x) * 4;
  float4 v = *(const float4*)(IC + i);
  *(ushort4*)(MH + i) = make_ushort4(f2h(v.x), f2h(v.y), f2h(v.z), f2h(v.w));
}

// Main: 1024 thr = 16 waves, wave owns 32 d-cols (2 frags) x all 64 n-rows (4 frags).
// V persists in LDS; B-frags stream from L2 (Mh, 1 MB/l fp16 -> XCD-L2-resident).
// Zero barriers in the K-loop. XCD-aware grid decode: XCD pair owns one l.
extern "C" __global__ __launch_bounds__(1024, 4)
void mel_main(const float* __restrict__ F, const float* __restrict__ MEAN,
              const float* __restrict__ W, const int* __restrict__ IDX,
              const unsigned short* __restrict__ MH,
              float* __restrict__ OUT) {
  extern __shared__ __align__(16) char lds[];
  __shared__ float red[16];
  const int t = threadIdx.x;
  const int lane = t & 63;
  const int w = t >> 6;          // 16 waves
  const int bid = blockIdx.x;
  const int xcd = bid & 7;
  const int l = xcd >> 1;
  const int bx = (bid >> 3) + ((xcd & 1) << 7);
  const int n0 = bx * BN;
  const int col0 = w * 32;       // wave's d-column base
  const int lrow = lane & 15;
  const int lke = (lane >> 4) << 3;  // k-offset 0,8,16,24

  // ---- stage V: gather mean row, subtract, fp16-convert into LDS
  {
    const int sn = t >> 4;          // 64 rows, 16 threads/row
    const int be = (t & 15) << 2;
    const int cls = IDX[n0 + sn];
    const float4* fr = (const float4*)(F + ((size_t)l * NDIM + n0 + sn) * DDIM);
    const float4* mr = (const float4*)(MEAN + ((size_t)l * CDIM + cls) * DDIM);
    float4 fv[8], mv[8];
#pragma unroll
    for (int j = 0; j < 8; ++j) fv[j] = fr[(be >> 2) + j * 16];
#pragma unroll
    for (int j = 0; j < 8; ++j) mv[j] = mr[(be >> 2) + j * 16];
#pragma unroll
    for (int j = 0; j < 8; ++j) {
      const int e = be + j * 64;
      *(ushort4*)(lds + vh_addr(sn, e)) =
          make_ushort4(f2h(fv[j].x - mv[j].x), f2h(fv[j].y - mv[j].y),
                       f2h(fv[j].z - mv[j].z), f2h(fv[j].w - mv[j].w));
    }
  }
  __syncthreads();  // only barrier before epilogue

  const size_t msz = (size_t)DDIM * DDIM;
  const unsigned short* mh_l = MH + (size_t)l * msz;

  f32x4 acc[4][2];  // [n-frag][d-frag]
#pragma unroll
  for (int i = 0; i < 4; ++i)
#pragma unroll
    for (int j = 0; j < 2; ++j) acc[i][j] = {0.f, 0.f, 0.f, 0.f};

  // ---- K-loop: A from LDS, B from L2 with depth-1 register prefetch. No barriers.
  const unsigned short* bp = mh_l + (size_t)(col0 + lrow) * DDIM + lke;
  f16x8 b0 = *(const f16x8*)(bp);
  f16x8 b1 = *(const f16x8*)(bp + 16 * DDIM);
#pragma unroll 2
  for (int s = 0; s < NSTEPS; ++s) {
    const int e0 = s * BK;
    f16x8 nb0, nb1;
    if (s < NSTEPS - 1) {
      const unsigned short* np = bp + (s + 1) * BK;
      nb0 = *(const f16x8*)(np);
      nb1 = *(const f16x8*)(np + 16 * DDIM);
    }
    f16x8 a0 = *(const f16x8*)(lds + vh_addr(lrow, e0 + lke));
    f16x8 a1 = *(const f16x8*)(lds + vh_addr(16 + lrow, e0 + lke));
    f16x8 a2 = *(const f16x8*)(lds + vh_addr(32 + lrow, e0 + lke));
    f16x8 a3 = *(const f16x8*)(lds + vh_addr(48 + lrow, e0 + lke));
    acc[0][0] = __builtin_amdgcn_mfma_f32_16x16x32_f16(a0, b0, acc[0][0], 0, 0, 0);
    acc[1][0] = __builtin_amdgcn_mfma_f32_16x16x32_f16(a1, b0, acc[1][0], 0, 0, 0);
    acc[2][0] = __builtin_amdgcn_mfma_f32_16x16x32_f16(a2, b0, acc[2][0], 0, 0, 0);
    acc[3][0] = __builtin_amdgcn_mfma_f32_16x16x32_f16(a3, b0, acc[3][0], 0, 0, 0);
    acc[0][1] = __builtin_amdgcn_mfma_f32_16x16x32_f16(a0, b1, acc[0][1], 0, 0, 0);
    acc[1][1] = __builtin_amdgcn_mfma_f32_16x16x32_f16(a1, b1, acc[1][1], 0, 0, 0);
    acc[2][1] = __builtin_amdgcn_mfma_f32_16x16x32_f16(a2, b1, acc[2][1], 0, 0, 0);
    acc[3][1] = __builtin_amdgcn_mfma_f32_16x16x32_f16(a3, b1, acc[3][1], 0, 0, 0);
    b0 = nb0; b1 = nb1;
  }

  // ---- epilogue: q = sum vh[n,dcol] * acc. C-frag: col=lane&15, row=(lane>>4)*4+r
  float tsum = 0.f;
#pragma unroll
  for (int nf = 0; nf < 4; ++nf) {
#pragma unroll
    for (int df = 0; df < 2; ++df) {
      const int dcol = col0 + df * 16 + lrow;
      const int nb = nf * 16 + ((lane >> 4) << 2);
      f32x4 c = acc[nf][df];
#pragma unroll
      for (int r = 0; r < 4; ++r) {
        unsigned short hv = *(const unsigned short*)(lds + vh_addr(nb + r, dcol));
        tsum += h2f(hv) * c[r];
      }
    }
  }
#pragma unroll
  for (int off = 32; off > 0; off >>= 1) tsum += __shfl_down(tsum, off);
  __syncthreads();
  if (lane == 0) red[w] = tsum;
  __syncthreads();
  if (t == 0) {
    float ssum = 0.f;
#pragma unroll
    for (int i = 0; i < 16; ++i) ssum += red[i];
    atomicAdd(OUT, ssum * (W[l] / (float)NDIM));
  }
}

// Correct-but-slow fp32 fallback (only if ws_size < WS_NEED).
extern "C" __global__ void mel_fallback(const float* __restrict__ F,
                                        const float* __restrict__ MEAN,
                                        const float* __restrict__ IC,
                                        const float* __restrict__ W,
                                        const int* __restrict__ IDX,
                                        float* __restrict__ OUT) {
  __shared__ float v[8][DDIM];
  __shared__ float red[256];
  const int t = threadIdx.x;
  const int l = blockIdx.y;
  const int n0 = blockIdx.x * 8;
  for (int i = t; i < 8 * DDIM; i += 256) {
    int n = i >> 9, e = i & 511;
    int c = IDX[n0 + n];
    v[n][e] = F[((size_t)l * NDIM + n0 + n) * DDIM + e] -
              MEAN[((size_t)l * CDIM + c) * DDIM + e];
  }
  __syncthreads();
  const float* icl = IC + ((size_t)l << 18);
  float part = 0.f;
  for (int rep = 0; rep < 2; ++rep) {
    int d = t + rep * 256;
    float s[8];
#pragma unroll
    for (int j = 0; j < 8; ++j) s[j] = 0.f;
    for (int e = 0; e < DDIM; ++e) {
      float m = icl[(size_t)d * DDIM + e];
#pragma unroll
      for (int j = 0; j < 8; ++j) s[j] += m * v[j][e];
    }
#pragma unroll
    for (int j = 0; j < 8; ++j) part += v[j][d] * s[j];
  }
  red[t] = part;
  __syncthreads();
  for (int o = 128; o > 0; o >>= 1) {
    if (t < o) red[t] += red[t + o];
    __syncthreads();
  }
  if (t == 0) atomicAdd(OUT, red[0] * (W[l] / (float)NDIM));
}

extern "C" void kernel_launch(void* const* d_in, const int* in_sizes, int n_in,
                              void* d_out, int out_size, void* d_ws, size_t ws_size,
                              hipStream_t stream) {
  const float* F = (const float*)d_in[0];
  const float* MEAN = (const float*)d_in[1];
  const float* IC = (const float*)d_in[2];
  const float* W = (const float*)d_in[3];
  const int* IDX = (const int*)d_in[4];
  float* OUT = (float*)d_out;

  hipMemsetAsync(d_out, 0, sizeof(float) * (size_t)out_size, stream);

  if (ws_size >= WS_NEED) {
    unsigned short* MH = (unsigned short*)d_ws;
    mel_mconv<<<dim3(1024), dim3(256), 0, stream>>>(IC, MH);
    (void)hipFuncSetAttribute(reinterpret_cast<const void*>(mel_main),
                              hipFuncAttributeMaxDynamicSharedMemorySize, LDS_BYTES);
    mel_main<<<dim3(1024), dim3(1024), LDS_BYTES, stream>>>(
        F, MEAN, W, IDX, MH, OUT);
  } else {
    mel_fallback<<<dim3(NDIM / 8, LDIM), dim3(256), 0, stream>>>(F, MEAN, IC, W, IDX, OUT);
  }
}